// Round 1
// baseline (517.359 us; speedup 1.0000x reference)
//
#include <hip/hip_runtime.h>

// PartialProductAccumulator: sequential ripple-add of 54 partial products
// over 108-bit lanes, carry-out dropped each step == sum mod 2^108.
// => per bit-column popcount (<=54) + single 108-step carry propagation.

#define N_PP    54
#define BITS    108
#define BATCH   16384
#define TB      32                  // batch rows per block
#define THREADS 256
#define ROW_F4  (BITS / 4)          // 27 float4 per row
#define CHUNK_F4 (TB * ROW_F4)      // 864 float4 per p-plane tile
#define SLOTS   4                   // ceil(864 / 256)

__global__ __launch_bounds__(THREADS)
void ppacc_kernel(const float* __restrict__ pps, float* __restrict__ out) {
    // +1 pad -> row stride 109 (mod 32 = 13, coprime) => conflict-free column walk
    __shared__ float counts[TB][BITS + 1];

    const int tid = threadIdx.x;
    const int b0  = blockIdx.x * TB;

    float4 acc[SLOTS];
#pragma unroll
    for (int s = 0; s < SLOTS; ++s) acc[s] = make_float4(0.f, 0.f, 0.f, 0.f);

    const float4* base = reinterpret_cast<const float4*>(pps) + (size_t)b0 * ROW_F4;
    const size_t  pstride = (size_t)BATCH * ROW_F4;   // float4s between p-planes

    // Hot loop: 54 planes x (<=4) coalesced float4 loads per thread.
    // Each thread's slots map to FIXED (batch,bit) columns across p -> register acc.
    for (int p = 0; p < N_PP; ++p) {
        const float4* plane = base + (size_t)p * pstride;
#pragma unroll
        for (int s = 0; s < SLOTS; ++s) {
            const int idx = tid + s * THREADS;
            if (idx < CHUNK_F4) {
                float4 v = plane[idx];
                acc[s].x += v.x;
                acc[s].y += v.y;
                acc[s].z += v.z;
                acc[s].w += v.w;
            }
        }
    }

    // Deposit per-column counts into LDS.
#pragma unroll
    for (int s = 0; s < SLOTS; ++s) {
        const int idx = tid + s * THREADS;
        if (idx < CHUNK_F4) {
            const int b   = idx / ROW_F4;
            const int bit = (idx % ROW_F4) * 4;
            counts[b][bit + 0] = acc[s].x;
            counts[b][bit + 1] = acc[s].y;
            counts[b][bit + 2] = acc[s].z;
            counts[b][bit + 3] = acc[s].w;
        }
    }
    __syncthreads();

    // 108-bit carry propagation: thread t handles batch row t.
    if (tid < TB) {
        int c = 0;
#pragma unroll
        for (int i = 0; i < BITS; ++i) {
            const int t = (int)counts[tid][i] + c;
            counts[tid][i] = (float)(t & 1);
            c = t >> 1;                      // carry out of bit 107 dropped
        }
    }
    __syncthreads();

    // Coalesced output: tile of 32 rows is contiguous (32*108 floats).
    float4* outp = reinterpret_cast<float4*>(out) + (size_t)b0 * ROW_F4;
#pragma unroll
    for (int s = 0; s < SLOTS; ++s) {
        const int idx = tid + s * THREADS;
        if (idx < CHUNK_F4) {
            const int b   = idx / ROW_F4;
            const int bit = (idx % ROW_F4) * 4;
            float4 v;
            v.x = counts[b][bit + 0];
            v.y = counts[b][bit + 1];
            v.z = counts[b][bit + 2];
            v.w = counts[b][bit + 3];
            outp[idx] = v;
        }
    }
}

extern "C" void kernel_launch(void* const* d_in, const int* in_sizes, int n_in,
                              void* d_out, int out_size, void* d_ws, size_t ws_size,
                              hipStream_t stream) {
    const float* pps = (const float*)d_in[0];
    float* out = (float*)d_out;
    const int grid = BATCH / TB;   // 512 blocks
    ppacc_kernel<<<grid, THREADS, 0, stream>>>(pps, out);
}

// Round 2
// 502.867 us; speedup vs baseline: 1.0288x; 1.0288x over previous
//
#include <hip/hip_runtime.h>

// PartialProductAccumulator: 54-step ripple add with dropped carry-out
// == sum of 54 partial products mod 2^108.
// K1: per-bit-column popcount (exact in fp32, max 54), streamed from HBM,
//     counts written into d_out (which is exactly BATCH*BITS floats).
// K2: in-place per-row 108-bit carry propagation (t = cnt + c; bit = t&1;
//     c = t>>1), one thread per row, all in registers.

#define N_PP   54
#define BITS   108
#define BATCH  16384
#define ROW_F4 (BITS / 4)                    // 27 float4 per row
#define PLANE_F4 ((size_t)BATCH * ROW_F4)    // 442368 float4 per p-plane

// ---------------- K1: column counts ----------------
// 864 blocks x 256 threads; each thread owns 2 float4 columns (idx, idx+256).
// Hot loop: 2 independent coalesced 16B loads per plane, register accumulate.
__global__ __launch_bounds__(256)
void count_kernel(const float4* __restrict__ pps, float4* __restrict__ cnt) {
    const size_t i0 = (size_t)blockIdx.x * 512 + threadIdx.x;
    const size_t i1 = i0 + 256;

    float4 a0 = make_float4(0.f, 0.f, 0.f, 0.f);
    float4 a1 = a0;

    const float4* p = pps;
    // software pipeline: keep next plane's loads in flight while accumulating
    float4 v0 = p[i0];
    float4 v1 = p[i1];
    for (int q = 1; q < N_PP; ++q) {
        p += PLANE_F4;
        float4 n0 = p[i0];
        float4 n1 = p[i1];
        a0.x += v0.x; a0.y += v0.y; a0.z += v0.z; a0.w += v0.w;
        a1.x += v1.x; a1.y += v1.y; a1.z += v1.z; a1.w += v1.w;
        v0 = n0; v1 = n1;
    }
    a0.x += v0.x; a0.y += v0.y; a0.z += v0.z; a0.w += v0.w;
    a1.x += v1.x; a1.y += v1.y; a1.z += v1.z; a1.w += v1.w;

    cnt[i0] = a0;
    cnt[i1] = a1;
}

// ---------------- K2: carry propagation ----------------
// One thread per batch row, 256 blocks x 64 threads. Row counts -> registers
// (27 independent float4 loads, latency-hidden), serial carry chain, write
// back in place (rows are disjoint across threads; K1->K2 stream-ordered).
__global__ __launch_bounds__(64)
void carry_kernel(float4* __restrict__ buf) {
    const int row = blockIdx.x * 64 + threadIdx.x;
    float4* rp = buf + (size_t)row * ROW_F4;

    float r[BITS];
#pragma unroll
    for (int j = 0; j < ROW_F4; ++j) {
        reinterpret_cast<float4*>(r)[j] = rp[j];
    }

    int c = 0;
#pragma unroll
    for (int i = 0; i < BITS; ++i) {
        const int t = (int)r[i] + c;
        r[i] = (float)(t & 1);
        c = t >> 1;                          // carry out of bit 107 dropped
    }

#pragma unroll
    for (int j = 0; j < ROW_F4; ++j) {
        rp[j] = reinterpret_cast<float4*>(r)[j];
    }
}

extern "C" void kernel_launch(void* const* d_in, const int* in_sizes, int n_in,
                              void* d_out, int out_size, void* d_ws, size_t ws_size,
                              hipStream_t stream) {
    const float4* pps = (const float4*)d_in[0];
    float4* out = (float4*)d_out;

    count_kernel<<<(int)(PLANE_F4 / 512), 256, 0, stream>>>(pps, out);
    carry_kernel<<<BATCH / 64, 64, 0, stream>>>(out);
}

// Round 3
// 469.058 us; speedup vs baseline: 1.1030x; 1.0721x over previous
//
#include <hip/hip_runtime.h>

// PartialProductAccumulator: 54-step ripple add with dropped carry-out
// == sum of 54 partial products mod 2^108.
// K1: per-bit-column popcount (exact in fp32, max 54), streamed from HBM.
//     1 float4 column per thread, 1728 blocks (=27 waves/CU), depth-2
//     software pipeline, nontemporal loads (one-pass 382 MB stream).
// K2: in-place per-row 108-bit carry propagation, one thread per row.

#define N_PP   54
#define BITS   108
#define BATCH  16384
#define ROW_F4 (BITS / 4)                    // 27 float4 per row
#define PLANE_F4 ((size_t)BATCH * ROW_F4)    // 442368 float4 per p-plane

typedef float vf4 __attribute__((ext_vector_type(4)));

// ---------------- K1: column counts ----------------
__global__ __launch_bounds__(256)
void count_kernel(const vf4* __restrict__ pps, vf4* __restrict__ cnt) {
    const size_t i0 = (size_t)blockIdx.x * 256 + threadIdx.x;
    const vf4* p = pps + i0;

    vf4 acc = (vf4)(0.f);

    // depth-2 pipeline: 2 loads in flight; acc waits on vmcnt(2)
    vf4 v0 = __builtin_nontemporal_load(p); p += PLANE_F4;
    vf4 v1 = __builtin_nontemporal_load(p);
#pragma unroll 4
    for (int q = 2; q < N_PP; ++q) {
        p += PLANE_F4;
        vf4 vn = __builtin_nontemporal_load(p);
        acc += v0;
        v0 = v1;
        v1 = vn;
    }
    acc += v0;
    acc += v1;

    cnt[i0] = acc;   // regular store: stays L2-warm for K2
}

// ---------------- K2: carry propagation ----------------
// One thread per batch row. Row counts -> registers (27 independent float4
// loads, mostly L2-hot), serial carry chain, write back in place (rows are
// disjoint across threads; K1->K2 stream-ordered).
__global__ __launch_bounds__(64)
void carry_kernel(vf4* __restrict__ buf) {
    const int row = blockIdx.x * 64 + threadIdx.x;
    vf4* rp = buf + (size_t)row * ROW_F4;

    float r[BITS];
#pragma unroll
    for (int j = 0; j < ROW_F4; ++j) {
        reinterpret_cast<vf4*>(r)[j] = rp[j];
    }

    int c = 0;
#pragma unroll
    for (int i = 0; i < BITS; ++i) {
        const int t = (int)r[i] + c;
        r[i] = (float)(t & 1);
        c = t >> 1;                          // carry out of bit 107 dropped
    }

#pragma unroll
    for (int j = 0; j < ROW_F4; ++j) {
        rp[j] = reinterpret_cast<vf4*>(r)[j];
    }
}

extern "C" void kernel_launch(void* const* d_in, const int* in_sizes, int n_in,
                              void* d_out, int out_size, void* d_ws, size_t ws_size,
                              hipStream_t stream) {
    const vf4* pps = (const vf4*)d_in[0];
    vf4* out = (vf4*)d_out;

    count_kernel<<<(int)(PLANE_F4 / 256), 256, 0, stream>>>(pps, out);
    carry_kernel<<<BATCH / 64, 64, 0, stream>>>(out);
}